// Round 13
// baseline (374.020 us; speedup 1.0000x reference)
//
#include <hip/hip_runtime.h>
#include <stdint.h>

#define B_   256
#define NPG  512
#define NG   131072
#define EPG  4096
#define NQPG 16
#define NQ   4096
#define EQPG 128
#define L_   2
#define HPITCH 136   // LDS row pitch in shorts (272 B)

typedef __attribute__((ext_vector_type(8))) short short8;
typedef __attribute__((ext_vector_type(4))) float floatx4;

__device__ inline float bf2f(unsigned short u){
    union { unsigned int i; float f; } x; x.i = ((unsigned int)u) << 16; return x.f;
}
__device__ inline unsigned short f2bf(float f){
    union { float f; unsigned int i; } x; x.f = f;
    unsigned int r = x.i + 0x7fff + ((x.i >> 16) & 1);  // RNE
    return (unsigned short)(r >> 16);
}
__device__ inline float d2(unsigned int a, unsigned int b, float c){
#if __has_builtin(__builtin_amdgcn_fdot2_f32_bf16)
    typedef __attribute__((ext_vector_type(2))) __bf16 bf16x2;
    union { unsigned int u; bf16x2 v; } xa, xb;
    xa.u = a; xb.u = b;
    return __builtin_amdgcn_fdot2_f32_bf16(xa.v, xb.v, c, false);
#else
    union { unsigned int u; float f; } la, ha, lb, hb;
    la.u = a << 16; ha.u = a & 0xffff0000u;
    lb.u = b << 16; hb.u = b & 0xffff0000u;
    return fmaf(la.f, lb.f, fmaf(ha.f, hb.f, c));
#endif
}
__device__ inline float dot8(uint4 a, uint4 b){
    return d2(a.x,b.x, d2(a.y,b.y, d2(a.z,b.z, d2(a.w,b.w, 0.f))));
}

// ---- transpose weights (fp32 in) to [N][K] bf16 ----
__global__ void k_transpose(const float* Wg, const float* Wq,
                            const float* W1r, const float* W2r,
                            unsigned short* WgT, unsigned short* WqT,
                            unsigned short* W1aT, unsigned short* W2rT){
    int idx = blockIdx.x*256 + threadIdx.x;
    if (idx < 8192){
        int k = idx >> 7, n = idx & 127; WgT[n*64 + k] = f2bf(Wg[idx]);
    } else if (idx < 16384){
        int i = idx - 8192; int k = i>>7, n = i&127; WqT[n*64+k] = f2bf(Wq[i]);
    } else if (idx < 49152){
        int i = idx - 16384; int l = i >> 14; int j = i & 16383; int k = j>>7, n = j&127;
        W1aT[l*16384 + n*128 + k] = f2bf(W1r[l*32768 + j]);
    } else {
        int i = idx - 49152; int l = i >> 14; int j = i & 16383; int k = j>>7, n = j&127;
        W2rT[l*16384 + n*128 + k] = f2bf(W2r[i]);
    }
}

// ---- one-shot CSR build + degree-sorted node permutation ----
__global__ __launch_bounds__(256) void k_csr(const int* __restrict__ g_src,
        const int* __restrict__ g_dst,
        unsigned short* __restrict__ csrc_g, int* __restrict__ off_g,
        float* __restrict__ degf, unsigned short* __restrict__ nodeperm){
    int g = blockIdx.x, t = threadIdx.x, lane = t & 63;
    __shared__ int cnt[NPG], woff[NPG];
    __shared__ int gscan[64];
    __shared__ int dh[64], dhoff[64];
    int gbase = g*NPG; size_t ebase = (size_t)g*EPG;
    for (int n=t;n<NPG;n+=256) cnt[n]=0;
    if (t<64) dh[t]=0;
    __syncthreads();
    for (int i=t;i<EPG;i+=256){
        int d = g_dst[ebase+i]-gbase;
        atomicAdd(&cnt[d],1);
    }
    __syncthreads();
    if (t < 64){
        int s=0;
        #pragma unroll
        for (int j=0;j<8;j++) s += cnt[t*8+j];
        int v=s;
        #pragma unroll
        for (int o=1;o<64;o<<=1){ int u=__shfl_up(v,o); if (lane>=o) v+=u; }
        gscan[t]=v;
    }
    __syncthreads();
    for (int n=t;n<NPG;n+=256){
        int grp=n>>3; int base = grp?gscan[grp-1]:0;
        for (int j=grp*8;j<n;j++) base+=cnt[j];
        off_g[g*NPG+n]=base; woff[n]=base;
        degf[gbase+n] = cnt[n]>0 ? 1.f : 0.f;
        atomicAdd(&dh[cnt[n] < 63 ? cnt[n] : 63], 1);
    }
    __syncthreads();
    if (t < 64){
        int v = dh[t];
        #pragma unroll
        for (int o=1;o<64;o<<=1){ int u=__shfl_up(v,o); if (lane>=o) v+=u; }
        dhoff[t] = v - dh[t];   // exclusive
    }
    __syncthreads();
    for (int n=t;n<NPG;n+=256){
        int d = cnt[n] < 63 ? cnt[n] : 63;
        int pos = atomicAdd(&dhoff[d],1);
        nodeperm[g*NPG+pos] = (unsigned short)n;
    }
    __syncthreads();
    for (int i=t;i<EPG;i+=256){
        int s = g_src[ebase+i]-gbase;
        int d = g_dst[ebase+i]-gbase;
        int pos = atomicAdd(&woff[d],1);
        csrc_g[ebase+pos]=(unsigned short)s;
    }
}

// ---- proj: out_bf16[M,128] = A_f32[M,64] @ WtT + bias ; optional row sumsq ----
__global__ __launch_bounds__(256) void k_proj(const float* __restrict__ A,
        const unsigned short* __restrict__ Wt, const float* __restrict__ bias,
        unsigned short* __restrict__ out, float* __restrict__ nrm2){
    const int K = 64;
    int wave = threadIdx.x >> 6, lane = threadIdx.x & 63;
    int quad = lane >> 4, l16 = lane & 15;
    int wrow = blockIdx.x*64 + wave*16;
    floatx4 acc[8];
    #pragma unroll
    for (int t=0;t<8;t++){
        #pragma unroll
        for (int r=0;r<4;r++) acc[t][r]=0.f;
    }
    #pragma unroll
    for (int ks = 0; ks < 2; ks++){
        int koff = ks*32 + quad*8;
        const float* ap = A + (size_t)(wrow+l16)*K + koff;
        short8 a;
        #pragma unroll
        for (int j=0;j<8;j++) a[j] = (short)f2bf(ap[j]);
        #pragma unroll
        for (int t=0;t<8;t++){
            short8 b = *(const short8*)(Wt + (size_t)(t*16+l16)*K + koff);
            acc[t] = __builtin_amdgcn_mfma_f32_16x16x32_bf16(a, b, acc[t], 0,0,0);
        }
    }
    float ss[4] = {0.f,0.f,0.f,0.f};
    #pragma unroll
    for (int t=0;t<8;t++){
        int col = t*16 + l16;
        float bv = bias[col];
        #pragma unroll
        for (int r=0;r<4;r++){
            float v = acc[t][r] + bv;
            out[(size_t)(wrow + quad*4 + r)*128 + col] = f2bf(v);
            ss[r] += v*v;
        }
    }
    if (nrm2){
        #pragma unroll
        for (int r=0;r<4;r++){
            #pragma unroll
            for (int o=1;o<16;o<<=1) ss[r] += __shfl_xor(ss[r], o);
        }
        if (l16==0){
            #pragma unroll
            for (int r=0;r<4;r++) nrm2[wrow + quad*4 + r] = ss[r];
        }
    }
}

// ---- query AGNN + Qg + fused cg2 = hqa @ W1r[l][128:256,:] ----
__global__ __launch_bounds__(128) void k_qagnn(unsigned short* __restrict__ h_q,
        const int* __restrict__ q_src, const int* __restrict__ q_dst,
        const float* __restrict__ beta_p, float* __restrict__ Qg,
        const float* __restrict__ W1r_l, float* __restrict__ cg2){
    int g = blockIdx.x, t = threadIdx.x;
    __shared__ float h[NQPG][132];
    __shared__ float e[EQPG], w[EQPG];
    __shared__ float inv[NQPG], mx[NQPG], den[NQPG];
    __shared__ int srcl[EQPG], dstl[EQPG], csr[EQPG];
    __shared__ int cnt[NQPG], off[NQPG], woff[NQPG];
    __shared__ float part[128];
    float beta = beta_p[0];
    for (int idx=t; idx<NQPG*128; idx+=128){
        int n = idx>>7, d = idx&127;
        h[n][d] = bf2f(h_q[(size_t)(g*NQPG+n)*128 + d]);
    }
    if (t<NQPG){ cnt[t]=0; mx[t]=0.f; den[t]=0.f; }
    __syncthreads();
    { int n=t>>3, c=t&7; float s=0;
      for (int d=c*16; d<c*16+16; d++){ float v=h[n][d]; s+=v*v; }
      part[t]=s; }
    __syncthreads();
    if (t<NQPG){ float s=0; for(int c=0;c<8;c++) s+=part[t*8+c]; inv[t]=rsqrtf(s+1e-24f); }
    __syncthreads();
    { int eidx = g*EQPG + t;
      int s = q_src[eidx] - g*NQPG, d = q_dst[eidx] - g*NQPG;
      srcl[t]=s; dstl[t]=d;
      float dot=0;
      for (int k=0;k<128;k++) dot += h[s][k]*h[d][k];
      e[t] = beta*dot*inv[s]*inv[d];
      atomicAdd(&cnt[d],1); }
    __syncthreads();
    if (t==0){ int o=0; for(int i=0;i<NQPG;i++){ off[i]=o; o+=cnt[i]; } }
    __syncthreads();
    if (t<NQPG){ woff[t]=off[t];
        if (cnt[t] > 0){
            float mm=-1e30f, dd=0.f;
            for (int j=0;j<EQPG;j++) if (dstl[j]==t) mm = fmaxf(mm, e[j]);
            for (int j=0;j<EQPG;j++) if (dstl[j]==t) dd += __expf(e[j]-mm);
            mx[t]=mm; den[t]=dd;
        } }
    __syncthreads();
    { int d = dstl[t];
      float dd = den[d];
      w[t] = dd > 0.f ? __expf(e[t]-mx[d]) / dd : 0.f;
      int pos = atomicAdd(&woff[d],1);
      csr[pos]=t; }
    __syncthreads();
    float aggr=0.f;
    { int d = t;
      for (int n=0;n<NQPG;n++){
          float acc=0.f;
          int o=off[n], c=cnt[n];
          for (int j=o;j<o+c;j++){ int ei=csr[j]; acc += w[ei]*h[srcl[ei]][d]; }
          h_q[(size_t)(g*NQPG+n)*128 + d] = f2bf(acc);
          aggr += acc;
      }
    }
    __syncthreads();
    part[t] = aggr*aggr;
    h[0][t] = aggr;
    __syncthreads();
    for (int s2=64; s2>0; s2>>=1){
        if (t<s2) part[t]+=part[t+s2];
        __syncthreads();
    }
    if (t==0) Qg[g]=part[0];
    float accc = 0.f;
    for (int k=0;k<128;k++) accc += h[0][k] * W1r_l[(128+k)*128 + t];
    cg2[g*128+t] = accc;
}

// ---- data-graph AGNN: one block/graph, full slice in LDS, node-centric fused
//      logit+gather; degree-sorted node order (anti-divergence) + 2-edge unroll ----
#define SMEM_GA 152592
__global__ __launch_bounds__(1024) void k_gagnn(const unsigned short* __restrict__ h_g,
        const float* __restrict__ nrm2, const float* __restrict__ Qg,
        const unsigned short* __restrict__ csrc_g, const int* __restrict__ off_g,
        const float* __restrict__ beta_p, const unsigned short* __restrict__ nodeperm,
        unsigned short* __restrict__ aout){
    extern __shared__ __align__(16) char smem[];
    unsigned short* hrows = (unsigned short*)smem;             // 512 x HPITCH (139264 B)
    float* inv            = (float*)(smem + 139264);           // 2048 B
    unsigned short* ssrc  = (unsigned short*)(smem + 141312);  // 8192 B
    int* offc             = (int*)(smem + 149504);             // 2052 B
    unsigned short* nprm  = (unsigned short*)(smem + 151556);  // 1024 B
    int g = blockIdx.x, t = threadIdx.x;
    int group = t >> 4, sl = t & 15;
    float beta = beta_p[0];
    float Q = Qg[g];
    int gbase = g*NPG;
    size_t ebase = (size_t)g*EPG;
    for (int i=t; i<8192; i+=1024){
        int row = i >> 4, col = i & 15;
        *(uint4*)(hrows + row*HPITCH + col*8) =
            *(const uint4*)(h_g + (size_t)(gbase+row)*128 + col*8);
    }
    for (int n=t; n<NPG; n+=1024){
        inv[n] = rsqrtf(nrm2[gbase+n] + Q + 1e-24f);
        nprm[n] = nodeperm[g*NPG+n];
    }
    for (int i=t; i<EPG; i+=1024) ssrc[i] = csrc_g[ebase+i];
    for (int n=t; n<=NPG; n+=1024) offc[n] = (n<NPG) ? off_g[g*NPG+n] : EPG;
    __syncthreads();
    // node-centric: 64 groups of 16 lanes; degree-sorted node order
    for (int idx = group; idx < NPG; idx += 64){
        int n = nprm[idx];
        int o = offc[n];
        int c = offc[n+1] - o;
        uint4 ov;
        if (c > 0){
            uint4 ud = *(const uint4*)(hrows + n*HPITCH + sl*8);
            float invn = inv[n];
            float ws0 = 0.f, ws1 = 0.f;
            float a0=0,a1=0,a2=0,a3=0,a4=0,a5=0,a6=0,a7=0;
            float b0=0,b1=0,b2=0,b3=0,b4=0,b5=0,b6=0,b7=0;
            int j = o, jend = o + c;
            for (; j+2 <= jend; j+=2){
                int s0 = ssrc[j], s1 = ssrc[j+1];
                uint4 u0 = *(const uint4*)(hrows + s0*HPITCH + sl*8);
                uint4 u1 = *(const uint4*)(hrows + s1*HPITCH + sl*8);
                float v0 = dot8(u0, ud);
                float v1 = dot8(u1, ud);
                v0 += __shfl_xor(v0,1); v1 += __shfl_xor(v1,1);
                v0 += __shfl_xor(v0,2); v1 += __shfl_xor(v1,2);
                v0 += __shfl_xor(v0,4); v1 += __shfl_xor(v1,4);
                v0 += __shfl_xor(v0,8); v1 += __shfl_xor(v1,8);
                float e0 = __expf(beta * (v0 + Q) * inv[s0] * invn);
                float e1 = __expf(beta * (v1 + Q) * inv[s1] * invn);
                ws0 += e0; ws1 += e1;
                a0 = fmaf(e0, bf2f((unsigned short)(u0.x&0xffff)), a0);
                a1 = fmaf(e0, bf2f((unsigned short)(u0.x>>16)),   a1);
                a2 = fmaf(e0, bf2f((unsigned short)(u0.y&0xffff)), a2);
                a3 = fmaf(e0, bf2f((unsigned short)(u0.y>>16)),   a3);
                a4 = fmaf(e0, bf2f((unsigned short)(u0.z&0xffff)), a4);
                a5 = fmaf(e0, bf2f((unsigned short)(u0.z>>16)),   a5);
                a6 = fmaf(e0, bf2f((unsigned short)(u0.w&0xffff)), a6);
                a7 = fmaf(e0, bf2f((unsigned short)(u0.w>>16)),   a7);
                b0 = fmaf(e1, bf2f((unsigned short)(u1.x&0xffff)), b0);
                b1 = fmaf(e1, bf2f((unsigned short)(u1.x>>16)),   b1);
                b2 = fmaf(e1, bf2f((unsigned short)(u1.y&0xffff)), b2);
                b3 = fmaf(e1, bf2f((unsigned short)(u1.y>>16)),   b3);
                b4 = fmaf(e1, bf2f((unsigned short)(u1.z&0xffff)), b4);
                b5 = fmaf(e1, bf2f((unsigned short)(u1.z>>16)),   b5);
                b6 = fmaf(e1, bf2f((unsigned short)(u1.w&0xffff)), b6);
                b7 = fmaf(e1, bf2f((unsigned short)(u1.w>>16)),   b7);
            }
            if (j < jend){
                int s0 = ssrc[j];
                uint4 u0 = *(const uint4*)(hrows + s0*HPITCH + sl*8);
                float v0 = dot8(u0, ud);
                v0 += __shfl_xor(v0,1); v0 += __shfl_xor(v0,2);
                v0 += __shfl_xor(v0,4); v0 += __shfl_xor(v0,8);
                float e0 = __expf(beta * (v0 + Q) * inv[s0] * invn);
                ws0 += e0;
                a0 = fmaf(e0, bf2f((unsigned short)(u0.x&0xffff)), a0);
                a1 = fmaf(e0, bf2f((unsigned short)(u0.x>>16)),   a1);
                a2 = fmaf(e0, bf2f((unsigned short)(u0.y&0xffff)), a2);
                a3 = fmaf(e0, bf2f((unsigned short)(u0.y>>16)),   a3);
                a4 = fmaf(e0, bf2f((unsigned short)(u0.z&0xffff)), a4);
                a5 = fmaf(e0, bf2f((unsigned short)(u0.z>>16)),   a5);
                a6 = fmaf(e0, bf2f((unsigned short)(u0.w&0xffff)), a6);
                a7 = fmaf(e0, bf2f((unsigned short)(u0.w>>16)),   a7);
            }
            float iw = __frcp_rn(ws0 + ws1);
            a0+=b0; a1+=b1; a2+=b2; a3+=b3; a4+=b4; a5+=b5; a6+=b6; a7+=b7;
            ov.x = (unsigned int)f2bf(a0*iw) | ((unsigned int)f2bf(a1*iw)<<16);
            ov.y = (unsigned int)f2bf(a2*iw) | ((unsigned int)f2bf(a3*iw)<<16);
            ov.z = (unsigned int)f2bf(a4*iw) | ((unsigned int)f2bf(a5*iw)<<16);
            ov.w = (unsigned int)f2bf(a6*iw) | ((unsigned int)f2bf(a7*iw)<<16);
        } else {
            ov.x=0; ov.y=0; ov.z=0; ov.w=0;
        }
        *(uint4*)(aout + (size_t)(gbase+n)*128 + sl*8) = ov;
    }
}

// ---- persistent fused MLP: one block per graph, weights staged in LDS ----
#define SMEM_MLP (3*128*136*2)
__global__ __launch_bounds__(512, 2) void k_mlp_p(const unsigned short* __restrict__ A,
        const unsigned short* __restrict__ W1t, const float* __restrict__ b1,
        const float* __restrict__ cg2, const float* __restrict__ degf,
        const unsigned short* __restrict__ W2t, const float* __restrict__ b2,
        unsigned short* __restrict__ out, float* __restrict__ nrm2){
    extern __shared__ __align__(16) char smem[];
    unsigned short* W1s = (unsigned short*)smem;       // 128 x 136
    unsigned short* W2s = W1s + 128*136;
    unsigned short* h1  = W2s + 128*136;
    int t = threadIdx.x;
    int g = blockIdx.x;
    #pragma unroll
    for (int p=0;p<4;p++){
        int flat = p*4096 + t*8;
        int n = flat>>7, k = flat&127;
        *(uint4*)(W1s + n*136 + k) = *(const uint4*)(W1t + n*128 + k);
        *(uint4*)(W2s + n*136 + k) = *(const uint4*)(W2t + n*128 + k);
    }
    __syncthreads();
    int wave = t>>6, lane = t&63, quad = lane>>4, l16 = lane&15;
    const float* cg = cg2 + (size_t)g*128;
    short8 af[4];
    {
        int wrow = g*512 + wave*16;
        #pragma unroll
        for (int ks=0;ks<4;ks++)
            af[ks] = *(const short8*)(A + (size_t)(wrow+l16)*128 + ks*32 + quad*8);
    }
    for (int it=0; it<4; it++){
        int wrow = g*512 + it*128 + wave*16;
        floatx4 acc[8];
        #pragma unroll
        for (int t8=0;t8<8;t8++){
            #pragma unroll
            for (int r=0;r<4;r++) acc[t8][r]=0.f;
        }
        #pragma unroll
        for (int ks=0;ks<4;ks++){
            int koff = ks*32 + quad*8;
            #pragma unroll
            for (int t8=0;t8<8;t8++){
                short8 b = *(const short8*)(W1s + (t8*16+l16)*136 + koff);
                acc[t8] = __builtin_amdgcn_mfma_f32_16x16x32_bf16(af[ks], b, acc[t8], 0,0,0);
            }
        }
        float dg[4];
        #pragma unroll
        for (int r=0;r<4;r++) dg[r] = degf[wrow + quad*4 + r];
        #pragma unroll
        for (int t8=0;t8<8;t8++){
            int col = t8*16 + l16;
            float bv = b1[col];
            float cv = cg[col];
            #pragma unroll
            for (int r=0;r<4;r++){
                float v = acc[t8][r] + bv + dg[r]*cv;
                v = v > 0.f ? v : 0.f;
                h1[(wave*16 + quad*4 + r)*136 + col] = f2bf(v);
            }
        }
        __syncthreads();
        short8 afn[4];
        if (it < 3){
            int wrow_n = g*512 + (it+1)*128 + wave*16;
            #pragma unroll
            for (int ks=0;ks<4;ks++)
                afn[ks] = *(const short8*)(A + (size_t)(wrow_n+l16)*128 + ks*32 + quad*8);
        }
        short8 hf[4];
        #pragma unroll
        for (int ks=0;ks<4;ks++) hf[ks] = *(const short8*)(h1 + (wave*16+l16)*136 + ks*32 + quad*8);
        floatx4 acc2[8];
        #pragma unroll
        for (int t8=0;t8<8;t8++){
            #pragma unroll
            for (int r=0;r<4;r++) acc2[t8][r]=0.f;
        }
        #pragma unroll
        for (int ks=0;ks<4;ks++){
            int koff = ks*32 + quad*8;
            #pragma unroll
            for (int t8=0;t8<8;t8++){
                short8 b = *(const short8*)(W2s + (t8*16+l16)*136 + koff);
                acc2[t8] = __builtin_amdgcn_mfma_f32_16x16x32_bf16(hf[ks], b, acc2[t8], 0,0,0);
            }
        }
        float ss[4] = {0.f,0.f,0.f,0.f};
        #pragma unroll
        for (int t8=0;t8<8;t8++){
            int col = t8*16 + l16;
            float bv = b2[col];
            #pragma unroll
            for (int r=0;r<4;r++){
                float v = acc2[t8][r] + bv;
                out[(size_t)(wrow + quad*4 + r)*128 + col] = f2bf(v);
                ss[r] += v*v;
            }
        }
        #pragma unroll
        for (int r=0;r<4;r++){
            #pragma unroll
            for (int o=1;o<16;o<<=1) ss[r] += __shfl_xor(ss[r], o);
        }
        if (l16==0){
            #pragma unroll
            for (int r=0;r<4;r++) nrm2[wrow + quad*4 + r] = ss[r];
        }
        __syncthreads();
        #pragma unroll
        for (int ks=0;ks<4;ks++) af[ks] = afn[ks];
    }
}

// ---- fused per-graph sum + predictor ----
__global__ __launch_bounds__(512) void k_hgpred(const unsigned short* __restrict__ h_g,
        const float* __restrict__ Wp1, const float* __restrict__ bp1,
        const float* __restrict__ Wp2, const float* __restrict__ bp2,
        float* __restrict__ y){
    __shared__ float red[32][128];
    __shared__ float hsum[128];
    __shared__ float red2[128];
    int g = blockIdx.x, t = threadIdx.x;
    int c = t & 15, r0 = t >> 4;
    float s[8];
    #pragma unroll
    for (int k=0;k<8;k++) s[k]=0.f;
    for (int i=0;i<16;i++){
        int row = r0 + i*32;
        uint4 u = *(const uint4*)(h_g + (size_t)(g*NPG + row)*128 + c*8);
        s[0] += bf2f((unsigned short)(u.x&0xffff)); s[1] += bf2f((unsigned short)(u.x>>16));
        s[2] += bf2f((unsigned short)(u.y&0xffff)); s[3] += bf2f((unsigned short)(u.y>>16));
        s[4] += bf2f((unsigned short)(u.z&0xffff)); s[5] += bf2f((unsigned short)(u.z>>16));
        s[6] += bf2f((unsigned short)(u.w&0xffff)); s[7] += bf2f((unsigned short)(u.w>>16));
    }
    #pragma unroll
    for (int k=0;k<8;k++) red[r0][c*8+k] = s[k];
    __syncthreads();
    if (t < 128){
        float a = 0.f;
        #pragma unroll
        for (int r=0;r<32;r++) a += red[r][t];
        hsum[t] = a;
    }
    __syncthreads();
    if (t < 128){
        float acc = bp1[t];
        for (int k=0;k<128;k++) acc += hsum[k]*Wp1[k*128+t];
        acc = fmaxf(acc, 0.f);
        red2[t] = acc * Wp2[t];
    }
    __syncthreads();
    for (int s2=64; s2>0; s2>>=1){
        if (t<s2) red2[t]+=red2[t+s2];
        __syncthreads();
    }
    if (t==0) y[g] = red2[0] + bp2[0];
}

extern "C" void kernel_launch(void* const* d_in, const int* in_sizes, int n_in,
                              void* d_out, int out_size, void* d_ws, size_t ws_size,
                              hipStream_t stream) {
    const float* X    = (const float*)d_in[0];
    const float* X_q  = (const float*)d_in[1];
    const int* g_src = (const int*)d_in[2];
    const int* g_dst = (const int*)d_in[3];
    const int* q_src = (const int*)d_in[5];
    const int* q_dst = (const int*)d_in[6];
    const float* Wg   = (const float*)d_in[8];
    const float* bg   = (const float*)d_in[9];
    const float* Wq   = (const float*)d_in[10];
    const float* bq   = (const float*)d_in[11];
    const float* betas_g = (const float*)d_in[12];
    const float* betas_q = (const float*)d_in[13];
    const float* W1r  = (const float*)d_in[14];
    const float* b1r  = (const float*)d_in[15];
    const float* W2r  = (const float*)d_in[16];
    const float* b2r  = (const float*)d_in[17];
    const float* Wp1  = (const float*)d_in[18];
    const float* bp1  = (const float*)d_in[19];
    const float* Wp2  = (const float*)d_in[20];
    const float* bp2  = (const float*)d_in[21];

    uint8_t* w = (uint8_t*)d_ws;
    unsigned short* h_g  = (unsigned short*)w;    w += (size_t)NG*128*2;
    unsigned short* h_q  = (unsigned short*)w;    w += (size_t)NQ*128*2;
    unsigned short* aout = (unsigned short*)w;    w += (size_t)NG*128*2;
    float* nrm2  = (float*)w;                     w += (size_t)NG*4;
    float* degf  = (float*)w;                     w += (size_t)NG*4;
    float* Qg    = (float*)w;                     w += (size_t)B_*4*4;
    float* cg2   = (float*)w;                     w += (size_t)B_*128*4;
    unsigned short* WgT   = (unsigned short*)w;   w += 8192*2;
    unsigned short* WqT   = (unsigned short*)w;   w += 8192*2;
    unsigned short* W1aT  = (unsigned short*)w;   w += 2*16384*2;
    unsigned short* W2rT  = (unsigned short*)w;   w += 2*16384*2;
    unsigned short* csrc_g = (unsigned short*)w;  w += (size_t)B_*EPG*2;
    unsigned short* nodeperm = (unsigned short*)w; w += (size_t)B_*NPG*2;
    int* off_g = (int*)w;                         w += (size_t)B_*NPG*4;

    static bool attr_done = false;
    if (!attr_done){
        hipFuncSetAttribute((const void*)k_mlp_p,
                            hipFuncAttributeMaxDynamicSharedMemorySize, SMEM_MLP);
        hipFuncSetAttribute((const void*)k_gagnn,
                            hipFuncAttributeMaxDynamicSharedMemorySize, SMEM_GA);
        attr_done = true;
    }

    k_transpose<<<320,256,0,stream>>>(Wg,Wq,W1r,W2r,WgT,WqT,W1aT,W2rT);
    k_csr<<<B_,256,0,stream>>>(g_src,g_dst,csrc_g,off_g,degf,nodeperm);
    k_proj<<<NG/64,256,0,stream>>>(X,   WgT, bg, h_g, nrm2);
    k_proj<<<NQ/64,256,0,stream>>>(X_q, WqT, bq, h_q, nullptr);
    for (int l=0;l<L_;l++){
        k_qagnn<<<B_,128,0,stream>>>(h_q, q_src, q_dst, betas_q + l, Qg,
                                     W1r + l*32768, cg2);
        k_gagnn<<<B_,1024,SMEM_GA,stream>>>(h_g, nrm2, Qg, csrc_g, off_g,
                                            betas_g + l, nodeperm, aout);
        k_mlp_p<<<B_,512,SMEM_MLP,stream>>>(aout, W1aT + l*16384, b1r + l*128, cg2, degf,
                                            W2rT + l*16384, b2r + l*128, h_g, nrm2);
    }
    k_hgpred<<<B_,512,0,stream>>>(h_g, Wp1, bp1, Wp2, bp2, (float*)d_out);
}

// Round 14
// 356.683 us; speedup vs baseline: 1.0486x; 1.0486x over previous
//
#include <hip/hip_runtime.h>
#include <stdint.h>

#define B_   256
#define NPG  512
#define NG   131072
#define EPG  4096
#define NQPG 16
#define NQ   4096
#define EQPG 128
#define L_   2
#define HPITCH 136   // LDS row pitch in shorts (272 B)

typedef __attribute__((ext_vector_type(8))) short short8;
typedef __attribute__((ext_vector_type(4))) float floatx4;

__device__ inline float bf2f(unsigned short u){
    union { unsigned int i; float f; } x; x.i = ((unsigned int)u) << 16; return x.f;
}
__device__ inline unsigned short f2bf(float f){
    union { float f; unsigned int i; } x; x.f = f;
    unsigned int r = x.i + 0x7fff + ((x.i >> 16) & 1);  // RNE
    return (unsigned short)(r >> 16);
}
__device__ inline float d2(unsigned int a, unsigned int b, float c){
#if __has_builtin(__builtin_amdgcn_fdot2_f32_bf16)
    typedef __attribute__((ext_vector_type(2))) __bf16 bf16x2;
    union { unsigned int u; bf16x2 v; } xa, xb;
    xa.u = a; xb.u = b;
    return __builtin_amdgcn_fdot2_f32_bf16(xa.v, xb.v, c, false);
#else
    union { unsigned int u; float f; } la, ha, lb, hb;
    la.u = a << 16; ha.u = a & 0xffff0000u;
    lb.u = b << 16; hb.u = b & 0xffff0000u;
    return fmaf(la.f, lb.f, fmaf(ha.f, hb.f, c));
#endif
}
__device__ inline float dot8(uint4 a, uint4 b){
    return d2(a.x,b.x, d2(a.y,b.y, d2(a.z,b.z, d2(a.w,b.w, 0.f))));
}

// 16-lane all-reduce sum via DPP (VALU pipe, ~8cyc/step) instead of __shfl_xor
// (LDS pipe, ~30cyc/step). xor1=quad_perm(1,0,3,2)=0xB1, xor2=quad_perm(2,3,0,1)=0x4E,
// xor4=row_half_mirror=0x141 (valid after xor1+xor2), xor8=row_ror:8=0x128.
__device__ inline float red16dpp(float v){
#if __has_builtin(__builtin_amdgcn_mov_dpp)
    int i;
    i = __builtin_amdgcn_mov_dpp(__float_as_int(v), 0xB1, 0xF, 0xF, true);
    v += __int_as_float(i);
    i = __builtin_amdgcn_mov_dpp(__float_as_int(v), 0x4E, 0xF, 0xF, true);
    v += __int_as_float(i);
    i = __builtin_amdgcn_mov_dpp(__float_as_int(v), 0x141, 0xF, 0xF, true);
    v += __int_as_float(i);
    i = __builtin_amdgcn_mov_dpp(__float_as_int(v), 0x128, 0xF, 0xF, true);
    v += __int_as_float(i);
    return v;
#else
    v += __shfl_xor(v,1); v += __shfl_xor(v,2);
    v += __shfl_xor(v,4); v += __shfl_xor(v,8);
    return v;
#endif
}

// ---- transpose weights (fp32 in) to [N][K] bf16 ----
__global__ void k_transpose(const float* Wg, const float* Wq,
                            const float* W1r, const float* W2r,
                            unsigned short* WgT, unsigned short* WqT,
                            unsigned short* W1aT, unsigned short* W2rT){
    int idx = blockIdx.x*256 + threadIdx.x;
    if (idx < 8192){
        int k = idx >> 7, n = idx & 127; WgT[n*64 + k] = f2bf(Wg[idx]);
    } else if (idx < 16384){
        int i = idx - 8192; int k = i>>7, n = i&127; WqT[n*64+k] = f2bf(Wq[i]);
    } else if (idx < 49152){
        int i = idx - 16384; int l = i >> 14; int j = i & 16383; int k = j>>7, n = j&127;
        W1aT[l*16384 + n*128 + k] = f2bf(W1r[l*32768 + j]);
    } else {
        int i = idx - 49152; int l = i >> 14; int j = i & 16383; int k = j>>7, n = j&127;
        W2rT[l*16384 + n*128 + k] = f2bf(W2r[i]);
    }
}

// ---- one-shot CSR build + degree-sorted node permutation ----
__global__ __launch_bounds__(256) void k_csr(const int* __restrict__ g_src,
        const int* __restrict__ g_dst,
        unsigned short* __restrict__ csrc_g, int* __restrict__ off_g,
        float* __restrict__ degf, unsigned short* __restrict__ nodeperm){
    int g = blockIdx.x, t = threadIdx.x, lane = t & 63;
    __shared__ int cnt[NPG], woff[NPG];
    __shared__ int gscan[64];
    __shared__ int dh[64], dhoff[64];
    int gbase = g*NPG; size_t ebase = (size_t)g*EPG;
    for (int n=t;n<NPG;n+=256) cnt[n]=0;
    if (t<64) dh[t]=0;
    __syncthreads();
    for (int i=t;i<EPG;i+=256){
        int d = g_dst[ebase+i]-gbase;
        atomicAdd(&cnt[d],1);
    }
    __syncthreads();
    if (t < 64){
        int s=0;
        #pragma unroll
        for (int j=0;j<8;j++) s += cnt[t*8+j];
        int v=s;
        #pragma unroll
        for (int o=1;o<64;o<<=1){ int u=__shfl_up(v,o); if (lane>=o) v+=u; }
        gscan[t]=v;
    }
    __syncthreads();
    for (int n=t;n<NPG;n+=256){
        int grp=n>>3; int base = grp?gscan[grp-1]:0;
        for (int j=grp*8;j<n;j++) base+=cnt[j];
        off_g[g*NPG+n]=base; woff[n]=base;
        degf[gbase+n] = cnt[n]>0 ? 1.f : 0.f;
        atomicAdd(&dh[cnt[n] < 63 ? cnt[n] : 63], 1);
    }
    __syncthreads();
    if (t < 64){
        int v = dh[t];
        #pragma unroll
        for (int o=1;o<64;o<<=1){ int u=__shfl_up(v,o); if (lane>=o) v+=u; }
        dhoff[t] = v - dh[t];   // exclusive
    }
    __syncthreads();
    for (int n=t;n<NPG;n+=256){
        int d = cnt[n] < 63 ? cnt[n] : 63;
        int pos = atomicAdd(&dhoff[d],1);
        nodeperm[g*NPG+pos] = (unsigned short)n;
    }
    __syncthreads();
    for (int i=t;i<EPG;i+=256){
        int s = g_src[ebase+i]-gbase;
        int d = g_dst[ebase+i]-gbase;
        int pos = atomicAdd(&woff[d],1);
        csrc_g[ebase+pos]=(unsigned short)s;
    }
}

// ---- proj: out_bf16[M,128] = A_f32[M,64] @ WtT + bias ; optional row sumsq ----
__global__ __launch_bounds__(256) void k_proj(const float* __restrict__ A,
        const unsigned short* __restrict__ Wt, const float* __restrict__ bias,
        unsigned short* __restrict__ out, float* __restrict__ nrm2){
    const int K = 64;
    int wave = threadIdx.x >> 6, lane = threadIdx.x & 63;
    int quad = lane >> 4, l16 = lane & 15;
    int wrow = blockIdx.x*64 + wave*16;
    floatx4 acc[8];
    #pragma unroll
    for (int t=0;t<8;t++){
        #pragma unroll
        for (int r=0;r<4;r++) acc[t][r]=0.f;
    }
    #pragma unroll
    for (int ks = 0; ks < 2; ks++){
        int koff = ks*32 + quad*8;
        const float* ap = A + (size_t)(wrow+l16)*K + koff;
        short8 a;
        #pragma unroll
        for (int j=0;j<8;j++) a[j] = (short)f2bf(ap[j]);
        #pragma unroll
        for (int t=0;t<8;t++){
            short8 b = *(const short8*)(Wt + (size_t)(t*16+l16)*K + koff);
            acc[t] = __builtin_amdgcn_mfma_f32_16x16x32_bf16(a, b, acc[t], 0,0,0);
        }
    }
    float ss[4] = {0.f,0.f,0.f,0.f};
    #pragma unroll
    for (int t=0;t<8;t++){
        int col = t*16 + l16;
        float bv = bias[col];
        #pragma unroll
        for (int r=0;r<4;r++){
            float v = acc[t][r] + bv;
            out[(size_t)(wrow + quad*4 + r)*128 + col] = f2bf(v);
            ss[r] += v*v;
        }
    }
    if (nrm2){
        #pragma unroll
        for (int r=0;r<4;r++){
            #pragma unroll
            for (int o=1;o<16;o<<=1) ss[r] += __shfl_xor(ss[r], o);
        }
        if (l16==0){
            #pragma unroll
            for (int r=0;r<4;r++) nrm2[wrow + quad*4 + r] = ss[r];
        }
    }
}

// ---- query AGNN + Qg + fused cg2 = hqa @ W1r[l][128:256,:] ----
__global__ __launch_bounds__(128) void k_qagnn(unsigned short* __restrict__ h_q,
        const int* __restrict__ q_src, const int* __restrict__ q_dst,
        const float* __restrict__ beta_p, float* __restrict__ Qg,
        const float* __restrict__ W1r_l, float* __restrict__ cg2){
    int g = blockIdx.x, t = threadIdx.x;
    __shared__ float h[NQPG][132];
    __shared__ float e[EQPG], w[EQPG];
    __shared__ float inv[NQPG], mx[NQPG], den[NQPG];
    __shared__ int srcl[EQPG], dstl[EQPG], csr[EQPG];
    __shared__ int cnt[NQPG], off[NQPG], woff[NQPG];
    __shared__ float part[128];
    float beta = beta_p[0];
    for (int idx=t; idx<NQPG*128; idx+=128){
        int n = idx>>7, d = idx&127;
        h[n][d] = bf2f(h_q[(size_t)(g*NQPG+n)*128 + d]);
    }
    if (t<NQPG){ cnt[t]=0; mx[t]=0.f; den[t]=0.f; }
    __syncthreads();
    { int n=t>>3, c=t&7; float s=0;
      for (int d=c*16; d<c*16+16; d++){ float v=h[n][d]; s+=v*v; }
      part[t]=s; }
    __syncthreads();
    if (t<NQPG){ float s=0; for(int c=0;c<8;c++) s+=part[t*8+c]; inv[t]=rsqrtf(s+1e-24f); }
    __syncthreads();
    { int eidx = g*EQPG + t;
      int s = q_src[eidx] - g*NQPG, d = q_dst[eidx] - g*NQPG;
      srcl[t]=s; dstl[t]=d;
      float dot=0;
      for (int k=0;k<128;k++) dot += h[s][k]*h[d][k];
      e[t] = beta*dot*inv[s]*inv[d];
      atomicAdd(&cnt[d],1); }
    __syncthreads();
    if (t==0){ int o=0; for(int i=0;i<NQPG;i++){ off[i]=o; o+=cnt[i]; } }
    __syncthreads();
    if (t<NQPG){ woff[t]=off[t];
        if (cnt[t] > 0){
            float mm=-1e30f, dd=0.f;
            for (int j=0;j<EQPG;j++) if (dstl[j]==t) mm = fmaxf(mm, e[j]);
            for (int j=0;j<EQPG;j++) if (dstl[j]==t) dd += __expf(e[j]-mm);
            mx[t]=mm; den[t]=dd;
        } }
    __syncthreads();
    { int d = dstl[t];
      float dd = den[d];
      w[t] = dd > 0.f ? __expf(e[t]-mx[d]) / dd : 0.f;
      int pos = atomicAdd(&woff[d],1);
      csr[pos]=t; }
    __syncthreads();
    float aggr=0.f;
    { int d = t;
      for (int n=0;n<NQPG;n++){
          float acc=0.f;
          int o=off[n], c=cnt[n];
          for (int j=o;j<o+c;j++){ int ei=csr[j]; acc += w[ei]*h[srcl[ei]][d]; }
          h_q[(size_t)(g*NQPG+n)*128 + d] = f2bf(acc);
          aggr += acc;
      }
    }
    __syncthreads();
    part[t] = aggr*aggr;
    h[0][t] = aggr;
    __syncthreads();
    for (int s2=64; s2>0; s2>>=1){
        if (t<s2) part[t]+=part[t+s2];
        __syncthreads();
    }
    if (t==0) Qg[g]=part[0];
    float accc = 0.f;
    for (int k=0;k<128;k++) accc += h[0][k] * W1r_l[(128+k)*128 + t];
    cg2[g*128+t] = accc;
}

// ---- data-graph AGNN: one block/graph, full slice in LDS, node-centric fused
//      logit+gather; degree-sorted order; DPP 16-lane reduce (off the LDS pipe) ----
#define SMEM_GA 152592
__global__ __launch_bounds__(1024) void k_gagnn(const unsigned short* __restrict__ h_g,
        const float* __restrict__ nrm2, const float* __restrict__ Qg,
        const unsigned short* __restrict__ csrc_g, const int* __restrict__ off_g,
        const float* __restrict__ beta_p, const unsigned short* __restrict__ nodeperm,
        unsigned short* __restrict__ aout){
    extern __shared__ __align__(16) char smem[];
    unsigned short* hrows = (unsigned short*)smem;             // 512 x HPITCH (139264 B)
    float* inv            = (float*)(smem + 139264);           // 2048 B
    unsigned short* ssrc  = (unsigned short*)(smem + 141312);  // 8192 B
    int* offc             = (int*)(smem + 149504);             // 2052 B
    unsigned short* nprm  = (unsigned short*)(smem + 151556);  // 1024 B
    int g = blockIdx.x, t = threadIdx.x;
    int group = t >> 4, sl = t & 15;
    float beta = beta_p[0];
    float Q = Qg[g];
    int gbase = g*NPG;
    size_t ebase = (size_t)g*EPG;
    for (int i=t; i<8192; i+=1024){
        int row = i >> 4, col = i & 15;
        *(uint4*)(hrows + row*HPITCH + col*8) =
            *(const uint4*)(h_g + (size_t)(gbase+row)*128 + col*8);
    }
    for (int n=t; n<NPG; n+=1024){
        inv[n] = rsqrtf(nrm2[gbase+n] + Q + 1e-24f);
        nprm[n] = nodeperm[g*NPG+n];
    }
    for (int i=t; i<EPG; i+=1024) ssrc[i] = csrc_g[ebase+i];
    for (int n=t; n<=NPG; n+=1024) offc[n] = (n<NPG) ? off_g[g*NPG+n] : EPG;
    __syncthreads();
    // node-centric: 64 groups of 16 lanes; degree-sorted node order
    for (int idx = group; idx < NPG; idx += 64){
        int n = nprm[idx];
        int o = offc[n];
        int c = offc[n+1] - o;
        uint4 ov;
        if (c > 0){
            uint4 ud = *(const uint4*)(hrows + n*HPITCH + sl*8);
            float invn = inv[n];
            float ws0 = 0.f, ws1 = 0.f;
            float a0=0,a1=0,a2=0,a3=0,a4=0,a5=0,a6=0,a7=0;
            float b0=0,b1=0,b2=0,b3=0,b4=0,b5=0,b6=0,b7=0;
            int j = o, jend = o + c;
            for (; j+2 <= jend; j+=2){
                int s0 = ssrc[j], s1 = ssrc[j+1];
                uint4 u0 = *(const uint4*)(hrows + s0*HPITCH + sl*8);
                uint4 u1 = *(const uint4*)(hrows + s1*HPITCH + sl*8);
                float v0 = red16dpp(dot8(u0, ud));
                float v1 = red16dpp(dot8(u1, ud));
                float e0 = __expf(beta * (v0 + Q) * inv[s0] * invn);
                float e1 = __expf(beta * (v1 + Q) * inv[s1] * invn);
                ws0 += e0; ws1 += e1;
                a0 = fmaf(e0, bf2f((unsigned short)(u0.x&0xffff)), a0);
                a1 = fmaf(e0, bf2f((unsigned short)(u0.x>>16)),   a1);
                a2 = fmaf(e0, bf2f((unsigned short)(u0.y&0xffff)), a2);
                a3 = fmaf(e0, bf2f((unsigned short)(u0.y>>16)),   a3);
                a4 = fmaf(e0, bf2f((unsigned short)(u0.z&0xffff)), a4);
                a5 = fmaf(e0, bf2f((unsigned short)(u0.z>>16)),   a5);
                a6 = fmaf(e0, bf2f((unsigned short)(u0.w&0xffff)), a6);
                a7 = fmaf(e0, bf2f((unsigned short)(u0.w>>16)),   a7);
                b0 = fmaf(e1, bf2f((unsigned short)(u1.x&0xffff)), b0);
                b1 = fmaf(e1, bf2f((unsigned short)(u1.x>>16)),   b1);
                b2 = fmaf(e1, bf2f((unsigned short)(u1.y&0xffff)), b2);
                b3 = fmaf(e1, bf2f((unsigned short)(u1.y>>16)),   b3);
                b4 = fmaf(e1, bf2f((unsigned short)(u1.z&0xffff)), b4);
                b5 = fmaf(e1, bf2f((unsigned short)(u1.z>>16)),   b5);
                b6 = fmaf(e1, bf2f((unsigned short)(u1.w&0xffff)), b6);
                b7 = fmaf(e1, bf2f((unsigned short)(u1.w>>16)),   b7);
            }
            if (j < jend){
                int s0 = ssrc[j];
                uint4 u0 = *(const uint4*)(hrows + s0*HPITCH + sl*8);
                float v0 = red16dpp(dot8(u0, ud));
                float e0 = __expf(beta * (v0 + Q) * inv[s0] * invn);
                ws0 += e0;
                a0 = fmaf(e0, bf2f((unsigned short)(u0.x&0xffff)), a0);
                a1 = fmaf(e0, bf2f((unsigned short)(u0.x>>16)),   a1);
                a2 = fmaf(e0, bf2f((unsigned short)(u0.y&0xffff)), a2);
                a3 = fmaf(e0, bf2f((unsigned short)(u0.y>>16)),   a3);
                a4 = fmaf(e0, bf2f((unsigned short)(u0.z&0xffff)), a4);
                a5 = fmaf(e0, bf2f((unsigned short)(u0.z>>16)),   a5);
                a6 = fmaf(e0, bf2f((unsigned short)(u0.w&0xffff)), a6);
                a7 = fmaf(e0, bf2f((unsigned short)(u0.w>>16)),   a7);
            }
            float iw = __frcp_rn(ws0 + ws1);
            a0+=b0; a1+=b1; a2+=b2; a3+=b3; a4+=b4; a5+=b5; a6+=b6; a7+=b7;
            ov.x = (unsigned int)f2bf(a0*iw) | ((unsigned int)f2bf(a1*iw)<<16);
            ov.y = (unsigned int)f2bf(a2*iw) | ((unsigned int)f2bf(a3*iw)<<16);
            ov.z = (unsigned int)f2bf(a4*iw) | ((unsigned int)f2bf(a5*iw)<<16);
            ov.w = (unsigned int)f2bf(a6*iw) | ((unsigned int)f2bf(a7*iw)<<16);
        } else {
            ov.x=0; ov.y=0; ov.z=0; ov.w=0;
        }
        *(uint4*)(aout + (size_t)(gbase+n)*128 + sl*8) = ov;
    }
}

// ---- persistent fused MLP: one block per graph, weights staged in LDS ----
#define SMEM_MLP (3*128*136*2)
__global__ __launch_bounds__(512, 2) void k_mlp_p(const unsigned short* __restrict__ A,
        const unsigned short* __restrict__ W1t, const float* __restrict__ b1,
        const float* __restrict__ cg2, const float* __restrict__ degf,
        const unsigned short* __restrict__ W2t, const float* __restrict__ b2,
        unsigned short* __restrict__ out, float* __restrict__ nrm2){
    extern __shared__ __align__(16) char smem[];
    unsigned short* W1s = (unsigned short*)smem;       // 128 x 136
    unsigned short* W2s = W1s + 128*136;
    unsigned short* h1  = W2s + 128*136;
    int t = threadIdx.x;
    int g = blockIdx.x;
    #pragma unroll
    for (int p=0;p<4;p++){
        int flat = p*4096 + t*8;
        int n = flat>>7, k = flat&127;
        *(uint4*)(W1s + n*136 + k) = *(const uint4*)(W1t + n*128 + k);
        *(uint4*)(W2s + n*136 + k) = *(const uint4*)(W2t + n*128 + k);
    }
    __syncthreads();
    int wave = t>>6, lane = t&63, quad = lane>>4, l16 = lane&15;
    const float* cg = cg2 + (size_t)g*128;
    short8 af[4];
    {
        int wrow = g*512 + wave*16;
        #pragma unroll
        for (int ks=0;ks<4;ks++)
            af[ks] = *(const short8*)(A + (size_t)(wrow+l16)*128 + ks*32 + quad*8);
    }
    for (int it=0; it<4; it++){
        int wrow = g*512 + it*128 + wave*16;
        floatx4 acc[8];
        #pragma unroll
        for (int t8=0;t8<8;t8++){
            #pragma unroll
            for (int r=0;r<4;r++) acc[t8][r]=0.f;
        }
        #pragma unroll
        for (int ks=0;ks<4;ks++){
            int koff = ks*32 + quad*8;
            #pragma unroll
            for (int t8=0;t8<8;t8++){
                short8 b = *(const short8*)(W1s + (t8*16+l16)*136 + koff);
                acc[t8] = __builtin_amdgcn_mfma_f32_16x16x32_bf16(af[ks], b, acc[t8], 0,0,0);
            }
        }
        float dg[4];
        #pragma unroll
        for (int r=0;r<4;r++) dg[r] = degf[wrow + quad*4 + r];
        #pragma unroll
        for (int t8=0;t8<8;t8++){
            int col = t8*16 + l16;
            float bv = b1[col];
            float cv = cg[col];
            #pragma unroll
            for (int r=0;r<4;r++){
                float v = acc[t8][r] + bv + dg[r]*cv;
                v = v > 0.f ? v : 0.f;
                h1[(wave*16 + quad*4 + r)*136 + col] = f2bf(v);
            }
        }
        __syncthreads();
        short8 afn[4];
        if (it < 3){
            int wrow_n = g*512 + (it+1)*128 + wave*16;
            #pragma unroll
            for (int ks=0;ks<4;ks++)
                afn[ks] = *(const short8*)(A + (size_t)(wrow_n+l16)*128 + ks*32 + quad*8);
        }
        short8 hf[4];
        #pragma unroll
        for (int ks=0;ks<4;ks++) hf[ks] = *(const short8*)(h1 + (wave*16+l16)*136 + ks*32 + quad*8);
        floatx4 acc2[8];
        #pragma unroll
        for (int t8=0;t8<8;t8++){
            #pragma unroll
            for (int r=0;r<4;r++) acc2[t8][r]=0.f;
        }
        #pragma unroll
        for (int ks=0;ks<4;ks++){
            int koff = ks*32 + quad*8;
            #pragma unroll
            for (int t8=0;t8<8;t8++){
                short8 b = *(const short8*)(W2s + (t8*16+l16)*136 + koff);
                acc2[t8] = __builtin_amdgcn_mfma_f32_16x16x32_bf16(hf[ks], b, acc2[t8], 0,0,0);
            }
        }
        float ss[4] = {0.f,0.f,0.f,0.f};
        #pragma unroll
        for (int t8=0;t8<8;t8++){
            int col = t8*16 + l16;
            float bv = b2[col];
            #pragma unroll
            for (int r=0;r<4;r++){
                float v = acc2[t8][r] + bv;
                out[(size_t)(wrow + quad*4 + r)*128 + col] = f2bf(v);
                ss[r] += v*v;
            }
        }
        #pragma unroll
        for (int r=0;r<4;r++){
            #pragma unroll
            for (int o=1;o<16;o<<=1) ss[r] += __shfl_xor(ss[r], o);
        }
        if (l16==0){
            #pragma unroll
            for (int r=0;r<4;r++) nrm2[wrow + quad*4 + r] = ss[r];
        }
        __syncthreads();
        #pragma unroll
        for (int ks=0;ks<4;ks++) af[ks] = afn[ks];
    }
}

// ---- fused per-graph sum + predictor ----
__global__ __launch_bounds__(512) void k_hgpred(const unsigned short* __restrict__ h_g,
        const float* __restrict__ Wp1, const float* __restrict__ bp1,
        const float* __restrict__ Wp2, const float* __restrict__ bp2,
        float* __restrict__ y){
    __shared__ float red[32][128];
    __shared__ float hsum[128];
    __shared__ float red2[128];
    int g = blockIdx.x, t = threadIdx.x;
    int c = t & 15, r0 = t >> 4;
    float s[8];
    #pragma unroll
    for (int k=0;k<8;k++) s[k]=0.f;
    for (int i=0;i<16;i++){
        int row = r0 + i*32;
        uint4 u = *(const uint4*)(h_g + (size_t)(g*NPG + row)*128 + c*8);
        s[0] += bf2f((unsigned short)(u.x&0xffff)); s[1] += bf2f((unsigned short)(u.x>>16));
        s[2] += bf2f((unsigned short)(u.y&0xffff)); s[3] += bf2f((unsigned short)(u.y>>16));
        s[4] += bf2f((unsigned short)(u.z&0xffff)); s[5] += bf2f((unsigned short)(u.z>>16));
        s[6] += bf2f((unsigned short)(u.w&0xffff)); s[7] += bf2f((unsigned short)(u.w>>16));
    }
    #pragma unroll
    for (int k=0;k<8;k++) red[r0][c*8+k] = s[k];
    __syncthreads();
    if (t < 128){
        float a = 0.f;
        #pragma unroll
        for (int r=0;r<32;r++) a += red[r][t];
        hsum[t] = a;
    }
    __syncthreads();
    if (t < 128){
        float acc = bp1[t];
        for (int k=0;k<128;k++) acc += hsum[k]*Wp1[k*128+t];
        acc = fmaxf(acc, 0.f);
        red2[t] = acc * Wp2[t];
    }
    __syncthreads();
    for (int s2=64; s2>0; s2>>=1){
        if (t<s2) red2[t]+=red2[t+s2];
        __syncthreads();
    }
    if (t==0) y[g] = red2[0] + bp2[0];
}

extern "C" void kernel_launch(void* const* d_in, const int* in_sizes, int n_in,
                              void* d_out, int out_size, void* d_ws, size_t ws_size,
                              hipStream_t stream) {
    const float* X    = (const float*)d_in[0];
    const float* X_q  = (const float*)d_in[1];
    const int* g_src = (const int*)d_in[2];
    const int* g_dst = (const int*)d_in[3];
    const int* q_src = (const int*)d_in[5];
    const int* q_dst = (const int*)d_in[6];
    const float* Wg   = (const float*)d_in[8];
    const float* bg   = (const float*)d_in[9];
    const float* Wq   = (const float*)d_in[10];
    const float* bq   = (const float*)d_in[11];
    const float* betas_g = (const float*)d_in[12];
    const float* betas_q = (const float*)d_in[13];
    const float* W1r  = (const float*)d_in[14];
    const float* b1r  = (const float*)d_in[15];
    const float* W2r  = (const float*)d_in[16];
    const float* b2r  = (const float*)d_in[17];
    const float* Wp1  = (const float*)d_in[18];
    const float* bp1  = (const float*)d_in[19];
    const float* Wp2  = (const float*)d_in[20];
    const float* bp2  = (const float*)d_in[21];

    uint8_t* w = (uint8_t*)d_ws;
    unsigned short* h_g  = (unsigned short*)w;    w += (size_t)NG*128*2;
    unsigned short* h_q  = (unsigned short*)w;    w += (size_t)NQ*128*2;
    unsigned short* aout = (unsigned short*)w;    w += (size_t)NG*128*2;
    float* nrm2  = (float*)w;                     w += (size_t)NG*4;
    float* degf  = (float*)w;                     w += (size_t)NG*4;
    float* Qg    = (float*)w;                     w += (size_t)B_*4*4;
    float* cg2   = (float*)w;                     w += (size_t)B_*128*4;
    unsigned short* WgT   = (unsigned short*)w;   w += 8192*2;
    unsigned short* WqT   = (unsigned short*)w;   w += 8192*2;
    unsigned short* W1aT  = (unsigned short*)w;   w += 2*16384*2;
    unsigned short* W2rT  = (unsigned short*)w;   w += 2*16384*2;
    unsigned short* csrc_g = (unsigned short*)w;  w += (size_t)B_*EPG*2;
    unsigned short* nodeperm = (unsigned short*)w; w += (size_t)B_*NPG*2;
    int* off_g = (int*)w;                         w += (size_t)B_*NPG*4;

    static bool attr_done = false;
    if (!attr_done){
        hipFuncSetAttribute((const void*)k_mlp_p,
                            hipFuncAttributeMaxDynamicSharedMemorySize, SMEM_MLP);
        hipFuncSetAttribute((const void*)k_gagnn,
                            hipFuncAttributeMaxDynamicSharedMemorySize, SMEM_GA);
        attr_done = true;
    }

    k_transpose<<<320,256,0,stream>>>(Wg,Wq,W1r,W2r,WgT,WqT,W1aT,W2rT);
    k_csr<<<B_,256,0,stream>>>(g_src,g_dst,csrc_g,off_g,degf,nodeperm);
    k_proj<<<NG/64,256,0,stream>>>(X,   WgT, bg, h_g, nrm2);
    k_proj<<<NQ/64,256,0,stream>>>(X_q, WqT, bq, h_q, nullptr);
    for (int l=0;l<L_;l++){
        k_qagnn<<<B_,128,0,stream>>>(h_q, q_src, q_dst, betas_q + l, Qg,
                                     W1r + l*32768, cg2);
        k_gagnn<<<B_,1024,SMEM_GA,stream>>>(h_g, nrm2, Qg, csrc_g, off_g,
                                            betas_g + l, nodeperm, aout);
        k_mlp_p<<<B_,512,SMEM_MLP,stream>>>(aout, W1aT + l*16384, b1r + l*128, cg2, degf,
                                            W2rT + l*16384, b2r + l*128, h_g, nrm2);
    }
    k_hgpred<<<B_,512,0,stream>>>(h_g, Wp1, bp1, Wp2, bp2, (float*)d_out);
}

// Round 15
// 301.899 us; speedup vs baseline: 1.2389x; 1.1815x over previous
//
#include <hip/hip_runtime.h>
#include <stdint.h>

#define B_   256
#define NPG  512
#define NG   131072
#define EPG  4096
#define NQPG 16
#define NQ   4096
#define EQPG 128
#define L_   2
#define HPITCH 136   // LDS row pitch in shorts (272 B)

typedef __attribute__((ext_vector_type(8))) short short8;
typedef __attribute__((ext_vector_type(4))) float floatx4;

__device__ inline float bf2f(unsigned short u){
    union { unsigned int i; float f; } x; x.i = ((unsigned int)u) << 16; return x.f;
}
__device__ inline unsigned short f2bf(float f){
    union { float f; unsigned int i; } x; x.f = f;
    unsigned int r = x.i + 0x7fff + ((x.i >> 16) & 1);  // RNE
    return (unsigned short)(r >> 16);
}
__device__ inline float d2(unsigned int a, unsigned int b, float c){
#if __has_builtin(__builtin_amdgcn_fdot2_f32_bf16)
    typedef __attribute__((ext_vector_type(2))) __bf16 bf16x2;
    union { unsigned int u; bf16x2 v; } xa, xb;
    xa.u = a; xb.u = b;
    return __builtin_amdgcn_fdot2_f32_bf16(xa.v, xb.v, c, false);
#else
    union { unsigned int u; float f; } la, ha, lb, hb;
    la.u = a << 16; ha.u = a & 0xffff0000u;
    lb.u = b << 16; hb.u = b & 0xffff0000u;
    return fmaf(la.f, lb.f, fmaf(ha.f, hb.f, c));
#endif
}
__device__ inline float dot8(uint4 a, uint4 b){
    return d2(a.x,b.x, d2(a.y,b.y, d2(a.z,b.z, d2(a.w,b.w, 0.f))));
}

// 16-lane all-reduce sum via DPP (VALU pipe) — R14-validated.
__device__ inline float red16dpp(float v){
#if __has_builtin(__builtin_amdgcn_mov_dpp)
    int i;
    i = __builtin_amdgcn_mov_dpp(__float_as_int(v), 0xB1, 0xF, 0xF, true);
    v += __int_as_float(i);
    i = __builtin_amdgcn_mov_dpp(__float_as_int(v), 0x4E, 0xF, 0xF, true);
    v += __int_as_float(i);
    i = __builtin_amdgcn_mov_dpp(__float_as_int(v), 0x141, 0xF, 0xF, true);
    v += __int_as_float(i);
    i = __builtin_amdgcn_mov_dpp(__float_as_int(v), 0x128, 0xF, 0xF, true);
    v += __int_as_float(i);
    return v;
#else
    v += __shfl_xor(v,1); v += __shfl_xor(v,2);
    v += __shfl_xor(v,4); v += __shfl_xor(v,8);
    return v;
#endif
}

// ---- transpose weights (fp32 in) to [N][K] bf16 ----
__global__ void k_transpose(const float* Wg, const float* Wq,
                            const float* W1r, const float* W2r,
                            unsigned short* WgT, unsigned short* WqT,
                            unsigned short* W1aT, unsigned short* W2rT){
    int idx = blockIdx.x*256 + threadIdx.x;
    if (idx < 8192){
        int k = idx >> 7, n = idx & 127; WgT[n*64 + k] = f2bf(Wg[idx]);
    } else if (idx < 16384){
        int i = idx - 8192; int k = i>>7, n = i&127; WqT[n*64+k] = f2bf(Wq[i]);
    } else if (idx < 49152){
        int i = idx - 16384; int l = i >> 14; int j = i & 16383; int k = j>>7, n = j&127;
        W1aT[l*16384 + n*128 + k] = f2bf(W1r[l*32768 + j]);
    } else {
        int i = idx - 49152; int l = i >> 14; int j = i & 16383; int k = j>>7, n = j&127;
        W2rT[l*16384 + n*128 + k] = f2bf(W2r[i]);
    }
}

// ---- one-shot CSR build + degree-sorted node permutation ----
__global__ __launch_bounds__(256) void k_csr(const int* __restrict__ g_src,
        const int* __restrict__ g_dst,
        unsigned short* __restrict__ csrc_g, int* __restrict__ off_g,
        float* __restrict__ degf, unsigned short* __restrict__ nodeperm){
    int g = blockIdx.x, t = threadIdx.x, lane = t & 63;
    __shared__ int cnt[NPG], woff[NPG];
    __shared__ int gscan[64];
    __shared__ int dh[64], dhoff[64];
    int gbase = g*NPG; size_t ebase = (size_t)g*EPG;
    for (int n=t;n<NPG;n+=256) cnt[n]=0;
    if (t<64) dh[t]=0;
    __syncthreads();
    for (int i=t;i<EPG;i+=256){
        int d = g_dst[ebase+i]-gbase;
        atomicAdd(&cnt[d],1);
    }
    __syncthreads();
    if (t < 64){
        int s=0;
        #pragma unroll
        for (int j=0;j<8;j++) s += cnt[t*8+j];
        int v=s;
        #pragma unroll
        for (int o=1;o<64;o<<=1){ int u=__shfl_up(v,o); if (lane>=o) v+=u; }
        gscan[t]=v;
    }
    __syncthreads();
    for (int n=t;n<NPG;n+=256){
        int grp=n>>3; int base = grp?gscan[grp-1]:0;
        for (int j=grp*8;j<n;j++) base+=cnt[j];
        off_g[g*NPG+n]=base; woff[n]=base;
        degf[gbase+n] = cnt[n]>0 ? 1.f : 0.f;
        atomicAdd(&dh[cnt[n] < 63 ? cnt[n] : 63], 1);
    }
    __syncthreads();
    if (t < 64){
        int v = dh[t];
        #pragma unroll
        for (int o=1;o<64;o<<=1){ int u=__shfl_up(v,o); if (lane>=o) v+=u; }
        dhoff[t] = v - dh[t];   // exclusive
    }
    __syncthreads();
    for (int n=t;n<NPG;n+=256){
        int d = cnt[n] < 63 ? cnt[n] : 63;
        int pos = atomicAdd(&dhoff[d],1);
        nodeperm[g*NPG+pos] = (unsigned short)n;
    }
    __syncthreads();
    for (int i=t;i<EPG;i+=256){
        int s = g_src[ebase+i]-gbase;
        int d = g_dst[ebase+i]-gbase;
        int pos = atomicAdd(&woff[d],1);
        csrc_g[ebase+pos]=(unsigned short)s;
    }
}

// ---- proj: out_bf16[M,128] = A_f32[M,64] @ WtT + bias ; optional row sumsq ----
__global__ __launch_bounds__(256) void k_proj(const float* __restrict__ A,
        const unsigned short* __restrict__ Wt, const float* __restrict__ bias,
        unsigned short* __restrict__ out, float* __restrict__ nrm2){
    const int K = 64;
    int wave = threadIdx.x >> 6, lane = threadIdx.x & 63;
    int quad = lane >> 4, l16 = lane & 15;
    int wrow = blockIdx.x*64 + wave*16;
    floatx4 acc[8];
    #pragma unroll
    for (int t=0;t<8;t++){
        #pragma unroll
        for (int r=0;r<4;r++) acc[t][r]=0.f;
    }
    #pragma unroll
    for (int ks = 0; ks < 2; ks++){
        int koff = ks*32 + quad*8;
        const float* ap = A + (size_t)(wrow+l16)*K + koff;
        short8 a;
        #pragma unroll
        for (int j=0;j<8;j++) a[j] = (short)f2bf(ap[j]);
        #pragma unroll
        for (int t=0;t<8;t++){
            short8 b = *(const short8*)(Wt + (size_t)(t*16+l16)*K + koff);
            acc[t] = __builtin_amdgcn_mfma_f32_16x16x32_bf16(a, b, acc[t], 0,0,0);
        }
    }
    float ss[4] = {0.f,0.f,0.f,0.f};
    #pragma unroll
    for (int t=0;t<8;t++){
        int col = t*16 + l16;
        float bv = bias[col];
        #pragma unroll
        for (int r=0;r<4;r++){
            float v = acc[t][r] + bv;
            out[(size_t)(wrow + quad*4 + r)*128 + col] = f2bf(v);
            ss[r] += v*v;
        }
    }
    if (nrm2){
        #pragma unroll
        for (int r=0;r<4;r++){
            #pragma unroll
            for (int o=1;o<16;o<<=1) ss[r] += __shfl_xor(ss[r], o);
        }
        if (l16==0){
            #pragma unroll
            for (int r=0;r<4;r++) nrm2[wrow + quad*4 + r] = ss[r];
        }
    }
}

// ---- fused per-graph layer: query AGNN prelude + data-graph AGNN ----
// LDS map (bytes):
//   hrows  0..139264   512 x HPITCH bf16 data rows
//   inv    139264..141312  (staged raw nrm2, then rsqrt(nrm2+Q))
//   ssrc   141312..149504
//   offc   149504..151556
//   nprm   151556..152580  (pad to 152592)
//   hqrows 152592..156944  16 x HPITCH bf16 query rows
//   eq     156944..157456
//   srcq   157456..157712
//   dstq   157712..157968
//   invq   157968..158032
//   denq   158032..158096
//   hqa    158096..158608
//   cg2s   158608..159120
//   Qacc   159120..159124
#define SMEM_GA 159136
__global__ __launch_bounds__(1024) void k_gagnn(const unsigned short* __restrict__ h_g,
        const float* __restrict__ nrm2, unsigned short* __restrict__ h_q,
        const int* __restrict__ q_src, const int* __restrict__ q_dst,
        const float* __restrict__ betaq_p, const float* __restrict__ betag_p,
        const unsigned short* __restrict__ csrc_g, const int* __restrict__ off_g,
        const unsigned short* __restrict__ nodeperm,
        const float* __restrict__ W1r_l, float* __restrict__ cg2,
        unsigned short* __restrict__ aout){
    extern __shared__ __align__(16) char smem[];
    unsigned short* hrows = (unsigned short*)smem;
    float* inv            = (float*)(smem + 139264);
    unsigned short* ssrc  = (unsigned short*)(smem + 141312);
    int* offc             = (int*)(smem + 149504);
    unsigned short* nprm  = (unsigned short*)(smem + 151556);
    unsigned short* hqrows= (unsigned short*)(smem + 152592);
    float* eq             = (float*)(smem + 156944);
    unsigned short* srcq  = (unsigned short*)(smem + 157456);
    unsigned short* dstq  = (unsigned short*)(smem + 157712);
    float* invq           = (float*)(smem + 157968);
    float* denq           = (float*)(smem + 158032);
    float* hqa            = (float*)(smem + 158096);
    float* cg2s           = (float*)(smem + 158608);
    float* QaccL          = (float*)(smem + 159120);
    int g = blockIdx.x, t = threadIdx.x;
    int group = t >> 4, sl = t & 15;
    float beta_q = betaq_p[0];
    float beta_g = betag_p[0];
    int gbase = g*NPG;
    size_t ebase = (size_t)g*EPG;
    // ---- stage everything ----
    for (int i=t; i<8192; i+=1024){
        int row = i >> 4, col = i & 15;
        *(uint4*)(hrows + row*HPITCH + col*8) =
            *(const uint4*)(h_g + (size_t)(gbase+row)*128 + col*8);
    }
    for (int n=t; n<NPG; n+=1024){
        inv[n] = nrm2[gbase+n];          // raw; rsqrt after Q known
        nprm[n] = nodeperm[g*NPG+n];
    }
    for (int i=t; i<EPG; i+=1024) ssrc[i] = csrc_g[ebase+i];
    for (int n=t; n<=NPG; n+=1024) offc[n] = (n<NPG) ? off_g[g*NPG+n] : EPG;
    if (t < 256){
        int row = t >> 4, col = t & 15;
        *(uint4*)(hqrows + row*HPITCH + col*8) =
            *(const uint4*)(h_q + (size_t)(g*NQPG+row)*128 + col*8);
    } else if (t < 384){
        int i = t - 256;
        srcq[i] = (unsigned short)(q_src[(size_t)g*EQPG+i] - g*NQPG);
        dstq[i] = (unsigned short)(q_dst[(size_t)g*EQPG+i] - g*NQPG);
    } else if (t < 400){
        denq[t-384] = 0.f;
    } else if (t == 400){
        QaccL[0] = 0.f;
    } else if (t >= 512 && t < 640){
        cg2s[t-512] = 0.f;
    }
    __syncthreads();
    // ---- query norms (16 subgroups) ----
    if (t < 256){
        int n = t >> 4;
        uint4 u = *(const uint4*)(hqrows + n*HPITCH + sl*8);
        float s = d2(u.x,u.x, d2(u.y,u.y, d2(u.z,u.z, d2(u.w,u.w, 0.f))));
        s = red16dpp(s);
        if (sl==0) invq[n] = rsqrtf(s + 1e-24f);
    }
    __syncthreads();
    // ---- query edge logits (no-max softmax, LDS atomic denominator) ----
    if (t < 256){
        int sg = t >> 4;
        for (int e = sg; e < EQPG; e += 16){
            int s = srcq[e], d = dstq[e];
            uint4 us = *(const uint4*)(hqrows + s*HPITCH + sl*8);
            uint4 ud = *(const uint4*)(hqrows + d*HPITCH + sl*8);
            float v = red16dpp(dot8(us, ud));
            if (sl==0){
                float ee = __expf(beta_q * v * invq[s] * invq[d]);
                eq[e] = ee;
                atomicAdd(&denq[d], ee);
            }
        }
    }
    __syncthreads();
    // ---- query aggregate (16 subgroups, one node each; regs) ----
    uint4 nq; nq.x=0; nq.y=0; nq.z=0; nq.w=0;
    int qn = t >> 4;
    if (t < 256){
        float wsum = denq[qn];
        if (wsum > 0.f){
            float a0=0,a1=0,a2=0,a3=0,a4=0,a5=0,a6=0,a7=0;
            for (int e=0;e<EQPG;e++){
                if (dstq[e] == qn){
                    float wg = eq[e];
                    int s = srcq[e];
                    uint4 u = *(const uint4*)(hqrows + s*HPITCH + sl*8);
                    a0 = fmaf(wg, bf2f((unsigned short)(u.x&0xffff)), a0);
                    a1 = fmaf(wg, bf2f((unsigned short)(u.x>>16)),   a1);
                    a2 = fmaf(wg, bf2f((unsigned short)(u.y&0xffff)), a2);
                    a3 = fmaf(wg, bf2f((unsigned short)(u.y>>16)),   a3);
                    a4 = fmaf(wg, bf2f((unsigned short)(u.z&0xffff)), a4);
                    a5 = fmaf(wg, bf2f((unsigned short)(u.z>>16)),   a5);
                    a6 = fmaf(wg, bf2f((unsigned short)(u.w&0xffff)), a6);
                    a7 = fmaf(wg, bf2f((unsigned short)(u.w>>16)),   a7);
                }
            }
            float iw = __frcp_rn(wsum);
            nq.x = (unsigned int)f2bf(a0*iw) | ((unsigned int)f2bf(a1*iw)<<16);
            nq.y = (unsigned int)f2bf(a2*iw) | ((unsigned int)f2bf(a3*iw)<<16);
            nq.z = (unsigned int)f2bf(a4*iw) | ((unsigned int)f2bf(a5*iw)<<16);
            nq.w = (unsigned int)f2bf(a6*iw) | ((unsigned int)f2bf(a7*iw)<<16);
        }
    }
    __syncthreads();   // all reads of old query rows complete
    if (t < 256){
        *(uint4*)(hqrows + qn*HPITCH + sl*8) = nq;
        *(uint4*)(h_q + (size_t)(g*NQPG+qn)*128 + sl*8) = nq;
    }
    __syncthreads();
    // ---- hqa + Q ----
    if (t < 128){
        float s = 0.f;
        for (int n=0;n<NQPG;n++) s += bf2f(hqrows[n*HPITCH + t]);
        hqa[t] = s;
        atomicAdd(&QaccL[0], s*s);
    }
    __syncthreads();
    float Q = QaccL[0];
    for (int n=t;n<NPG;n+=1024) inv[n] = rsqrtf(inv[n] + Q + 1e-24f);
    {
        int j = t & 127, kc = t >> 7;
        float p = 0.f;
        for (int k = kc*16; k < kc*16+16; k++)
            p = fmaf(hqa[k], W1r_l[(size_t)(128+k)*128 + j], p);
        atomicAdd(&cg2s[j], p);
    }
    __syncthreads();
    if (t < 128) cg2[(size_t)g*128 + t] = cg2s[t];
    // ---- data-graph node-centric fused logit+gather (R12-14 proven) ----
    for (int idx = group; idx < NPG; idx += 64){
        int n = nprm[idx];
        int o = offc[n];
        int c = offc[n+1] - o;
        uint4 ov;
        if (c > 0){
            uint4 ud = *(const uint4*)(hrows + n*HPITCH + sl*8);
            float invn = inv[n];
            float ws0 = 0.f, ws1 = 0.f;
            float a0=0,a1=0,a2=0,a3=0,a4=0,a5=0,a6=0,a7=0;
            float b0=0,b1=0,b2=0,b3=0,b4=0,b5=0,b6=0,b7=0;
            int j = o, jend = o + c;
            for (; j+2 <= jend; j+=2){
                int s0 = ssrc[j], s1 = ssrc[j+1];
                uint4 u0 = *(const uint4*)(hrows + s0*HPITCH + sl*8);
                uint4 u1 = *(const uint4*)(hrows + s1*HPITCH + sl*8);
                float v0 = red16dpp(dot8(u0, ud));
                float v1 = red16dpp(dot8(u1, ud));
                float e0 = __expf(beta_g * (v0 + Q) * inv[s0] * invn);
                float e1 = __expf(beta_g * (v1 + Q) * inv[s1] * invn);
                ws0 += e0; ws1 += e1;
                a0 = fmaf(e0, bf2f((unsigned short)(u0.x&0xffff)), a0);
                a1 = fmaf(e0, bf2f((unsigned short)(u0.x>>16)),   a1);
                a2 = fmaf(e0, bf2f((unsigned short)(u0.y&0xffff)), a2);
                a3 = fmaf(e0, bf2f((unsigned short)(u0.y>>16)),   a3);
                a4 = fmaf(e0, bf2f((unsigned short)(u0.z&0xffff)), a4);
                a5 = fmaf(e0, bf2f((unsigned short)(u0.z>>16)),   a5);
                a6 = fmaf(e0, bf2f((unsigned short)(u0.w&0xffff)), a6);
                a7 = fmaf(e0, bf2f((unsigned short)(u0.w>>16)),   a7);
                b0 = fmaf(e1, bf2f((unsigned short)(u1.x&0xffff)), b0);
                b1 = fmaf(e1, bf2f((unsigned short)(u1.x>>16)),   b1);
                b2 = fmaf(e1, bf2f((unsigned short)(u1.y&0xffff)), b2);
                b3 = fmaf(e1, bf2f((unsigned short)(u1.y>>16)),   b3);
                b4 = fmaf(e1, bf2f((unsigned short)(u1.z&0xffff)), b4);
                b5 = fmaf(e1, bf2f((unsigned short)(u1.z>>16)),   b5);
                b6 = fmaf(e1, bf2f((unsigned short)(u1.w&0xffff)), b6);
                b7 = fmaf(e1, bf2f((unsigned short)(u1.w>>16)),   b7);
            }
            if (j < jend){
                int s0 = ssrc[j];
                uint4 u0 = *(const uint4*)(hrows + s0*HPITCH + sl*8);
                float v0 = red16dpp(dot8(u0, ud));
                float e0 = __expf(beta_g * (v0 + Q) * inv[s0] * invn);
                ws0 += e0;
                a0 = fmaf(e0, bf2f((unsigned short)(u0.x&0xffff)), a0);
                a1 = fmaf(e0, bf2f((unsigned short)(u0.x>>16)),   a1);
                a2 = fmaf(e0, bf2f((unsigned short)(u0.y&0xffff)), a2);
                a3 = fmaf(e0, bf2f((unsigned short)(u0.y>>16)),   a3);
                a4 = fmaf(e0, bf2f((unsigned short)(u0.z&0xffff)), a4);
                a5 = fmaf(e0, bf2f((unsigned short)(u0.z>>16)),   a5);
                a6 = fmaf(e0, bf2f((unsigned short)(u0.w&0xffff)), a6);
                a7 = fmaf(e0, bf2f((unsigned short)(u0.w>>16)),   a7);
            }
            float iw = __frcp_rn(ws0 + ws1);
            a0+=b0; a1+=b1; a2+=b2; a3+=b3; a4+=b4; a5+=b5; a6+=b6; a7+=b7;
            ov.x = (unsigned int)f2bf(a0*iw) | ((unsigned int)f2bf(a1*iw)<<16);
            ov.y = (unsigned int)f2bf(a2*iw) | ((unsigned int)f2bf(a3*iw)<<16);
            ov.z = (unsigned int)f2bf(a4*iw) | ((unsigned int)f2bf(a5*iw)<<16);
            ov.w = (unsigned int)f2bf(a6*iw) | ((unsigned int)f2bf(a7*iw)<<16);
        } else {
            ov.x=0; ov.y=0; ov.z=0; ov.w=0;
        }
        *(uint4*)(aout + (size_t)(gbase+n)*128 + sl*8) = ov;
    }
}

// ---- persistent fused MLP: one block per graph, weights staged in LDS ----
#define SMEM_MLP (3*128*136*2)
__global__ __launch_bounds__(512, 2) void k_mlp_p(const unsigned short* __restrict__ A,
        const unsigned short* __restrict__ W1t, const float* __restrict__ b1,
        const float* __restrict__ cg2, const float* __restrict__ degf,
        const unsigned short* __restrict__ W2t, const float* __restrict__ b2,
        unsigned short* __restrict__ out, float* __restrict__ nrm2){
    extern __shared__ __align__(16) char smem[];
    unsigned short* W1s = (unsigned short*)smem;       // 128 x 136
    unsigned short* W2s = W1s + 128*136;
    unsigned short* h1  = W2s + 128*136;
    int t = threadIdx.x;
    int g = blockIdx.x;
    #pragma unroll
    for (int p=0;p<4;p++){
        int flat = p*4096 + t*8;
        int n = flat>>7, k = flat&127;
        *(uint4*)(W1s + n*136 + k) = *(const uint4*)(W1t + n*128 + k);
        *(uint4*)(W2s + n*136 + k) = *(const uint4*)(W2t + n*128 + k);
    }
    __syncthreads();
    int wave = t>>6, lane = t&63, quad = lane>>4, l16 = lane&15;
    const float* cg = cg2 + (size_t)g*128;
    short8 af[4];
    {
        int wrow = g*512 + wave*16;
        #pragma unroll
        for (int ks=0;ks<4;ks++)
            af[ks] = *(const short8*)(A + (size_t)(wrow+l16)*128 + ks*32 + quad*8);
    }
    for (int it=0; it<4; it++){
        int wrow = g*512 + it*128 + wave*16;
        floatx4 acc[8];
        #pragma unroll
        for (int t8=0;t8<8;t8++){
            #pragma unroll
            for (int r=0;r<4;r++) acc[t8][r]=0.f;
        }
        #pragma unroll
        for (int ks=0;ks<4;ks++){
            int koff = ks*32 + quad*8;
            #pragma unroll
            for (int t8=0;t8<8;t8++){
                short8 b = *(const short8*)(W1s + (t8*16+l16)*136 + koff);
                acc[t8] = __builtin_amdgcn_mfma_f32_16x16x32_bf16(af[ks], b, acc[t8], 0,0,0);
            }
        }
        float dg[4];
        #pragma unroll
        for (int r=0;r<4;r++) dg[r] = degf[wrow + quad*4 + r];
        #pragma unroll
        for (int t8=0;t8<8;t8++){
            int col = t8*16 + l16;
            float bv = b1[col];
            float cv = cg[col];
            #pragma unroll
            for (int r=0;r<4;r++){
                float v = acc[t8][r] + bv + dg[r]*cv;
                v = v > 0.f ? v : 0.f;
                h1[(wave*16 + quad*4 + r)*136 + col] = f2bf(v);
            }
        }
        __syncthreads();
        short8 afn[4];
        if (it < 3){
            int wrow_n = g*512 + (it+1)*128 + wave*16;
            #pragma unroll
            for (int ks=0;ks<4;ks++)
                afn[ks] = *(const short8*)(A + (size_t)(wrow_n+l16)*128 + ks*32 + quad*8);
        }
        short8 hf[4];
        #pragma unroll
        for (int ks=0;ks<4;ks++) hf[ks] = *(const short8*)(h1 + (wave*16+l16)*136 + ks*32 + quad*8);
        floatx4 acc2[8];
        #pragma unroll
        for (int t8=0;t8<8;t8++){
            #pragma unroll
            for (int r=0;r<4;r++) acc2[t8][r]=0.f;
        }
        #pragma unroll
        for (int ks=0;ks<4;ks++){
            int koff = ks*32 + quad*8;
            #pragma unroll
            for (int t8=0;t8<8;t8++){
                short8 b = *(const short8*)(W2s + (t8*16+l16)*136 + koff);
                acc2[t8] = __builtin_amdgcn_mfma_f32_16x16x32_bf16(hf[ks], b, acc2[t8], 0,0,0);
            }
        }
        float ss[4] = {0.f,0.f,0.f,0.f};
        #pragma unroll
        for (int t8=0;t8<8;t8++){
            int col = t8*16 + l16;
            float bv = b2[col];
            #pragma unroll
            for (int r=0;r<4;r++){
                float v = acc2[t8][r] + bv;
                out[(size_t)(wrow + quad*4 + r)*128 + col] = f2bf(v);
                ss[r] += v*v;
            }
        }
        #pragma unroll
        for (int r=0;r<4;r++){
            #pragma unroll
            for (int o=1;o<16;o<<=1) ss[r] += __shfl_xor(ss[r], o);
        }
        if (l16==0){
            #pragma unroll
            for (int r=0;r<4;r++) nrm2[wrow + quad*4 + r] = ss[r];
        }
        __syncthreads();
        #pragma unroll
        for (int ks=0;ks<4;ks++) af[ks] = afn[ks];
    }
}

// ---- fused per-graph sum + predictor ----
__global__ __launch_bounds__(512) void k_hgpred(const unsigned short* __restrict__ h_g,
        const float* __restrict__ Wp1, const float* __restrict__ bp1,
        const float* __restrict__ Wp2, const float* __restrict__ bp2,
        float* __restrict__ y){
    __shared__ float red[32][128];
    __shared__ float hsum[128];
    __shared__ float red2[128];
    int g = blockIdx.x, t = threadIdx.x;
    int c = t & 15, r0 = t >> 4;
    float s[8];
    #pragma unroll
    for (int k=0;k<8;k++) s[k]=0.f;
    for (int i=0;i<16;i++){
        int row = r0 + i*32;
        uint4 u = *(const uint4*)(h_g + (size_t)(g*NPG + row)*128 + c*8);
        s[0] += bf2f((unsigned short)(u.x&0xffff)); s[1] += bf2f((unsigned short)(u.x>>16));
        s[2] += bf2f((unsigned short)(u.y&0xffff)); s[3] += bf2f((unsigned short)(u.y>>16));
        s[4] += bf2f((unsigned short)(u.z&0xffff)); s[5] += bf2f((unsigned short)(u.z>>16));
        s[6] += bf2f((unsigned short)(u.w&0xffff)); s[7] += bf2f((unsigned short)(u.w>>16));
    }
    #pragma unroll
    for (int k=0;k<8;k++) red[r0][c*8+k] = s[k];
    __syncthreads();
    if (t < 128){
        float a = 0.f;
        #pragma unroll
        for (int r=0;r<32;r++) a += red[r][t];
        hsum[t] = a;
    }
    __syncthreads();
    if (t < 128){
        float acc = bp1[t];
        for (int k=0;k<128;k++) acc += hsum[k]*Wp1[k*128+t];
        acc = fmaxf(acc, 0.f);
        red2[t] = acc * Wp2[t];
    }
    __syncthreads();
    for (int s2=64; s2>0; s2>>=1){
        if (t<s2) red2[t]+=red2[t+s2];
        __syncthreads();
    }
    if (t==0) y[g] = red2[0] + bp2[0];
}

extern "C" void kernel_launch(void* const* d_in, const int* in_sizes, int n_in,
                              void* d_out, int out_size, void* d_ws, size_t ws_size,
                              hipStream_t stream) {
    const float* X    = (const float*)d_in[0];
    const float* X_q  = (const float*)d_in[1];
    const int* g_src = (const int*)d_in[2];
    const int* g_dst = (const int*)d_in[3];
    const int* q_src = (const int*)d_in[5];
    const int* q_dst = (const int*)d_in[6];
    const float* Wg   = (const float*)d_in[8];
    const float* bg   = (const float*)d_in[9];
    const float* Wq   = (const float*)d_in[10];
    const float* bq   = (const float*)d_in[11];
    const float* betas_g = (const float*)d_in[12];
    const float* betas_q = (const float*)d_in[13];
    const float* W1r  = (const float*)d_in[14];
    const float* b1r  = (const float*)d_in[15];
    const float* W2r  = (const float*)d_in[16];
    const float* b2r  = (const float*)d_in[17];
    const float* Wp1  = (const float*)d_in[18];
    const float* bp1  = (const float*)d_in[19];
    const float* Wp2  = (const float*)d_in[20];
    const float* bp2  = (const float*)d_in[21];

    uint8_t* w = (uint8_t*)d_ws;
    unsigned short* h_g  = (unsigned short*)w;    w += (size_t)NG*128*2;
    unsigned short* h_q  = (unsigned short*)w;    w += (size_t)NQ*128*2;
    unsigned short* aout = (unsigned short*)w;    w += (size_t)NG*128*2;
    float* nrm2  = (float*)w;                     w += (size_t)NG*4;
    float* degf  = (float*)w;                     w += (size_t)NG*4;
    float* cg2   = (float*)w;                     w += (size_t)B_*128*4;
    unsigned short* WgT   = (unsigned short*)w;   w += 8192*2;
    unsigned short* WqT   = (unsigned short*)w;   w += 8192*2;
    unsigned short* W1aT  = (unsigned short*)w;   w += 2*16384*2;
    unsigned short* W2rT  = (unsigned short*)w;   w += 2*16384*2;
    unsigned short* csrc_g = (unsigned short*)w;  w += (size_t)B_*EPG*2;
    unsigned short* nodeperm = (unsigned short*)w; w += (size_t)B_*NPG*2;
    int* off_g = (int*)w;                         w += (size_t)B_*NPG*4;

    static bool attr_done = false;
    if (!attr_done){
        hipFuncSetAttribute((const void*)k_mlp_p,
                            hipFuncAttributeMaxDynamicSharedMemorySize, SMEM_MLP);
        hipFuncSetAttribute((const void*)k_gagnn,
                            hipFuncAttributeMaxDynamicSharedMemorySize, SMEM_GA);
        attr_done = true;
    }

    k_transpose<<<320,256,0,stream>>>(Wg,Wq,W1r,W2r,WgT,WqT,W1aT,W2rT);
    k_csr<<<B_,256,0,stream>>>(g_src,g_dst,csrc_g,off_g,degf,nodeperm);
    k_proj<<<NG/64,256,0,stream>>>(X,   WgT, bg, h_g, nrm2);
    k_proj<<<NQ/64,256,0,stream>>>(X_q, WqT, bq, h_q, nullptr);
    for (int l=0;l<L_;l++){
        k_gagnn<<<B_,1024,SMEM_GA,stream>>>(h_g, nrm2, h_q, q_src, q_dst,
                                            betas_q + l, betas_g + l,
                                            csrc_g, off_g, nodeperm,
                                            W1r + l*32768, cg2, aout);
        k_mlp_p<<<B_,512,SMEM_MLP,stream>>>(aout, W1aT + l*16384, b1r + l*128, cg2, degf,
                                            W2rT + l*16384, b2r + l*128, h_g, nrm2);
    }
    k_hgpred<<<B_,512,0,stream>>>(h_g, Wp1, bp1, Wp2, bp2, (float*)d_out);
}